// Round 1
// baseline (618.862 us; speedup 1.0000x reference)
//
#include <hip/hip_runtime.h>
#include <math.h>

#define EPSF 1e-6f
#define NUM_V 10
#define W_IMG 2000
#define H_IMG 1500
#define HW_IMG (W_IMG * H_IMG)

__device__ __forceinline__ void cross3(const float a[3], const float b[3], float c[3]) {
    c[0] = a[1] * b[2] - a[2] * b[1];
    c[1] = a[2] * b[0] - a[0] * b[2];
    c[2] = a[0] * b[1] - a[1] * b[0];
}
__device__ __forceinline__ float dot3(const float a[3], const float b[3]) {
    return a[0] * b[0] + a[1] * b[1] + a[2] * b[2];
}
__device__ __forceinline__ float norm3(const float a[3]) {
    return sqrtf(a[0] * a[0] + a[1] * a[1] + a[2] * a[2]);
}

// Bilinear sample from planar (3,H,W) image at normalized uv in [0,1).
__device__ __forceinline__ void sample_img(const float* __restrict__ img, float u, float v,
                                           float out[3]) {
    float x = u * (float)(W_IMG - 1);
    float y = v * (float)(H_IMG - 1);
    float fx = floorf(x), fy = floorf(y);
    int x0 = (int)fx, y0 = (int)fy;
    int x1 = min(x0 + 1, W_IMG - 1);
    int y1 = min(y0 + 1, H_IMG - 1);
    float wx = x - fx, wy = y - fy;
    float w00 = (1.f - wx) * (1.f - wy);
    float w01 = wx * (1.f - wy);
    float w10 = (1.f - wx) * wy;
    float w11 = wx * wy;
    int i00 = y0 * W_IMG + x0;
    int i01 = y0 * W_IMG + x1;
    int i10 = y1 * W_IMG + x0;
    int i11 = y1 * W_IMG + x1;
#pragma unroll
    for (int c = 0; c < 3; ++c) {
        const float* b = img + c * HW_IMG;
        out[c] = b[i00] * w00 + b[i01] * w01 + b[i10] * w10 + b[i11] * w11;
    }
}

// Zero accumulators (ws is poisoned 0xAA each launch) and build T = K2h @ E2 @ inv(E1).
__global__ void init_kernel(const float* __restrict__ K2, const float* __restrict__ E1,
                            const float* __restrict__ E2, double* __restrict__ acc,
                            unsigned long long* __restrict__ cnt, float* __restrict__ T) {
    if (threadIdx.x != 0) return;
    acc[0] = 0.0;
    acc[1] = 0.0;
    acc[2] = 0.0;
    *cnt = 0ull;
    // Gauss-Jordan inverse of E1 (double)
    double M[4][8];
    for (int i = 0; i < 4; ++i)
        for (int j = 0; j < 4; ++j) {
            M[i][j] = (double)E1[i * 4 + j];
            M[i][j + 4] = (i == j) ? 1.0 : 0.0;
        }
    for (int col = 0; col < 4; ++col) {
        int piv = col;
        double best = fabs(M[col][col]);
        for (int r = col + 1; r < 4; ++r) {
            double v = fabs(M[r][col]);
            if (v > best) { best = v; piv = r; }
        }
        if (piv != col)
            for (int j = 0; j < 8; ++j) {
                double t = M[col][j];
                M[col][j] = M[piv][j];
                M[piv][j] = t;
            }
        double d = M[col][col];
        for (int j = 0; j < 8; ++j) M[col][j] /= d;
        for (int r = 0; r < 4; ++r) {
            if (r == col) continue;
            double f = M[r][col];
            for (int j = 0; j < 8; ++j) M[r][j] -= f * M[col][j];
        }
    }
    // E = E2 @ inv(E1)
    double E[4][4];
    for (int i = 0; i < 4; ++i)
        for (int j = 0; j < 4; ++j) {
            double s = 0.0;
            for (int k = 0; k < 4; ++k) s += (double)E2[i * 4 + k] * M[k][j + 4];
            E[i][j] = s;
        }
    // K2h = eye(4) with [:3,:3] = K2 ;  T = K2h @ E
    for (int i = 0; i < 4; ++i)
        for (int j = 0; j < 4; ++j) {
            double s = 0.0;
            if (i < 3) {
                for (int k = 0; k < 3; ++k) s += (double)K2[i * 3 + k] * E[k][j];
            } else {
                s = E[3][j];
            }
            T[i * 4 + j] = (float)s;
        }
}

__global__ __launch_bounds__(256) void edge_kernel(
    const float* __restrict__ ep, const float* __restrict__ K1, const float* __restrict__ rgb1,
    const float* __restrict__ rgb2, const float* __restrict__ T, double* __restrict__ acc,
    unsigned long long* __restrict__ cnt) {
    __shared__ float s_geo[11];  // start3, dir3, up3, len, denom
    __shared__ int s_nsamp;
    __shared__ float s_wsum[4];

    const int e = blockIdx.x;
    if (threadIdx.x == 0) {
        const float* P = ep + (size_t)e * 12;
        float p0[3] = {P[0], P[1], P[2]};
        float p1[3] = {P[3], P[4], P[5]};
        float p2[3] = {P[6], P[7], P[8]};
        float p3[3] = {P[9], P[10], P[11]};
        float cd[3] = {p1[0] - p0[0], p1[1] - p0[1], p1[2] - p0[2]};
        float nd[3] = {p3[0] - p1[0], p3[1] - p1[1], p3[2] - p1[2]};
        float pd[3] = {p0[0] - p2[0], p0[1] - p2[1], p0[2] - p2[2]};
        float ce[3] = {cd[0] + EPSF, cd[1] + EPSF, cd[2] + EPSF};
        float clen = norm3(ce);
        float dir[3] = {cd[0] / clen, cd[1] / clen, cd[2] / clen};
        float cn[3];
        cross3(dir, nd, cn);
        float n1 = norm3(cn) + EPSF;
        cn[0] /= n1; cn[1] /= n1; cn[2] /= n1;
        if (cn[2] > 0.f) { cn[0] = -cn[0]; cn[1] = -cn[1]; cn[2] = -cn[2]; }
        float up[3];
        cross3(cn, dir, up);
        float n2 = norm3(up) + EPSF;
        up[0] /= n2; up[1] /= n2; up[2] /= n2;
        float pn[3];
        cross3(pd, dir, pn);
        float n3 = norm3(pn) + EPSF;
        pn[0] /= n3; pn[1] /= n3; pn[2] /= n3;
        float obs[3];
        cross3(p0, p1, obs);
        float n4 = norm3(obs) + EPSF;
        obs[0] /= n4; obs[1] /= n4; obs[2] /= n4;
        int nh = (int)floorf(clen / 0.05f);
        nh = max(2, min(1000, nh));
        float nl = 1.f - dot3(cn, pn);
        float snp = fminf(fabsf(dot3(up, obs)), 0.5f);
        float zl = 1.f - snp * 2.f;
        atomicAdd(&acc[1], (double)nl);
        atomicAdd(&acc[2], (double)zl);
        atomicAdd(cnt, (unsigned long long)(nh * NUM_V));
        s_geo[0] = p0[0]; s_geo[1] = p0[1]; s_geo[2] = p0[2];
        s_geo[3] = dir[0]; s_geo[4] = dir[1]; s_geo[5] = dir[2];
        s_geo[6] = up[0]; s_geo[7] = up[1]; s_geo[8] = up[2];
        s_geo[9] = clen;
        s_geo[10] = (float)(nh - 1);
        s_nsamp = nh * NUM_V;
    }
    __syncthreads();

    const float sx = s_geo[0], sy = s_geo[1], sz = s_geo[2];
    const float dx = s_geo[3], dyr = s_geo[4], dz = s_geo[5];
    const float ux = s_geo[6], uy = s_geo[7], uz = s_geo[8];
    const float len = s_geo[9];
    const float denom = s_geo[10];
    const int nsamp = s_nsamp;

    const float k00 = K1[0], k01 = K1[1], k02 = K1[2];
    const float k10 = K1[3], k11 = K1[4], k12 = K1[5];
    const float k20 = K1[6], k21 = K1[7], k22 = K1[8];
    const float t00 = T[0], t01 = T[1], t02 = T[2], t03 = T[3];
    const float t10 = T[4], t11 = T[5], t12 = T[6], t13 = T[7];
    const float t20 = T[8], t21 = T[9], t22 = T[10], t23 = T[11];

    float lsum = 0.f;
    for (int i = threadIdx.x; i < nsamp; i += 256) {
        int px = i / NUM_V;
        int dy = i - px * NUM_V;
        float cx = ((float)px / denom) * len;
        float cy = ((float)dy / 9.0f) * 0.5f;
        float X = fmaf(dx, cx, fmaf(ux, cy, sx));
        float Y = fmaf(dyr, cx, fmaf(uy, cy, sy));
        float Z = fmaf(dz, cx, fmaf(uz, cy, sz));
        // camera 1 projection
        float w1 = fmaf(k20, X, fmaf(k21, Y, k22 * Z));
        float u1 = fminf(fmaxf(fmaf(k00, X, fmaf(k01, Y, k02 * Z)) / w1, 0.f), 0.999999f);
        float v1 = fminf(fmaxf(fmaf(k10, X, fmaf(k11, Y, k12 * Z)) / w1, 0.f), 0.999999f);
        float s1[3];
        sample_img(rgb1, u1, v1, s1);
        // camera 2 projection (homogeneous)
        float w2 = fmaf(t20, X, fmaf(t21, Y, fmaf(t22, Z, t23)));
        float u2 = fminf(fmaxf(fmaf(t00, X, fmaf(t01, Y, fmaf(t02, Z, t03))) / w2, 0.f), 0.999999f);
        float v2 = fminf(fmaxf(fmaf(t10, X, fmaf(t11, Y, fmaf(t12, Z, t13))) / w2, 0.f), 0.999999f);
        float s2[3];
        sample_img(rgb2, u2, v2, s2);
        float d0 = s1[0] - s2[0];
        float d1 = s1[1] - s2[1];
        float d2 = s1[2] - s2[2];
        lsum += d0 * d0 + d1 * d1 + d2 * d2;
    }

    // wave (64) reduction then cross-wave via LDS
#pragma unroll
    for (int off = 32; off > 0; off >>= 1) lsum += __shfl_down(lsum, off);
    const int wave = threadIdx.x >> 6;
    const int lane = threadIdx.x & 63;
    if (lane == 0) s_wsum[wave] = lsum;
    __syncthreads();
    if (threadIdx.x == 0) {
        float tot = s_wsum[0] + s_wsum[1] + s_wsum[2] + s_wsum[3];
        atomicAdd(&acc[0], (double)tot);
    }
}

__global__ void finalize_kernel(const double* __restrict__ acc,
                                const unsigned long long* __restrict__ cnt,
                                float* __restrict__ out, int N) {
    if (threadIdx.x == 0) {
        double c = (double)(*cnt) * 3.0;
        out[0] = (float)(acc[0] / c);
        out[1] = (float)(acc[1] / (double)N * 0.5);
        out[2] = (float)(acc[2] / (double)N);
    }
}

extern "C" void kernel_launch(void* const* d_in, const int* in_sizes, int n_in, void* d_out,
                              int out_size, void* d_ws, size_t ws_size, hipStream_t stream) {
    const float* ep = (const float*)d_in[0];
    const float* K1 = (const float*)d_in[1];
    const float* K2 = (const float*)d_in[2];
    const float* E1 = (const float*)d_in[3];
    const float* E2 = (const float*)d_in[4];
    const float* rgb1 = (const float*)d_in[5];
    const float* rgb2 = (const float*)d_in[6];
    float* out = (float*)d_out;
    const int N = in_sizes[0] / 12;

    double* acc = (double*)d_ws;                            // 3 doubles: sim, normal, normalization
    unsigned long long* cnt = (unsigned long long*)(acc + 3);
    float* T = (float*)(acc + 4);                           // 16 floats

    init_kernel<<<1, 64, 0, stream>>>(K2, E1, E2, acc, cnt, T);
    edge_kernel<<<N, 256, 0, stream>>>(ep, K1, rgb1, rgb2, T, acc, cnt);
    finalize_kernel<<<1, 64, 0, stream>>>(acc, cnt, out, N);
}